// Round 9
// baseline (321.785 us; speedup 1.0000x reference)
//
#include <hip/hip_runtime.h>

// ---------------------------------------------------------------------------
// CapsuleSequenceToGraph, fp32 in/out. B=64, T={128,512,256,256}, n=32, d=16.
// Identity: b_k[b,t,n] = <Vcum_k[b,n,:], pri[b,t,n,:]>, Vcum_k = sum_{i<k} v_i.
//
// 2 dispatches. pri_kernel: R4-proven MFMA structure, t-major
// [mod][t][b][n*16+d]. route_kernel v3: one block per (mod,b), 4 passes
// block-local; t-rows streamed through a per-wave 8-slot LDS ring staged
// with global_load_lds width=16 (keeps ~6 rows in flight per wave without
// VGPR pressure; no barriers in the t-loop since slots are wave-private).
// Lessons: ~25us/dependent-dispatch (R2-R4); grid.sync ~115us (R6); b-major
// strided stores wreck pri (R7); VGPR-rotating prefetch never pipelines,
// ~6KB/CU in flight, 6.9 B/cyc/CU (R8) -> global_load_lds ring.
//
// ws: [0, 75497472) pri bf16 only.
// ---------------------------------------------------------------------------

typedef __attribute__((ext_vector_type(8))) short short8;
typedef __attribute__((ext_vector_type(4))) float floatx4;

static __device__ __forceinline__ unsigned short f2bf(float f) {
  union { float f; unsigned int i; } v;
  v.f = f;
  unsigned int x = v.i;
  return (unsigned short)((x + 0x7fffu + ((x >> 16) & 1u)) >> 16);  // RNE
}

static __device__ __forceinline__ void stage16(const unsigned short* g,
                                               unsigned short* l) {
  __builtin_amdgcn_global_load_lds(
      (const __attribute__((address_space(1))) unsigned int*)g,
      (__attribute__((address_space(3))) unsigned int*)l, 16, 0, 0);
}

// ---------------------------------------------------------------------------
// pri = x @ W per t, bf16 MFMA 16x16x32 (R4 structure). Block = (t, 16-n
// half): M=64(b) x N=256(nd) x K=64(j). Stores via per-wave LDS transpose.
// ---------------------------------------------------------------------------
__global__ __launch_bounds__(256) void pri_kernel(
    const float* __restrict__ x0, const float* __restrict__ x1,
    const float* __restrict__ x2, const float* __restrict__ x3,
    const float* __restrict__ w0, const float* __restrict__ w1,
    const float* __restrict__ w2, const float* __restrict__ w3,
    unsigned short* __restrict__ priAll) {
  __shared__ unsigned short wb[256 * 72];   // [nd_local][j] bf16, pitch 72
  __shared__ unsigned short sc[4][16][136]; // per-wave store-transpose scratch

  int blk = blockIdx.x;
  int tid = threadIdx.x;

  int tpair = blk >> 1, half = blk & 1;
  const float* x;
  const float* W;
  unsigned short* priT;
  int T, t;
  if (tpair < 128)      { x = x0; W = w0; priT = priAll;               T = 128; t = tpair; }
  else if (tpair < 640) { x = x1; W = w1; priT = priAll + 4194304ull;  T = 512; t = tpair - 128; }
  else if (tpair < 896) { x = x2; W = w2; priT = priAll + 20971520ull; T = 256; t = tpair - 640; }
  else                  { x = x3; W = w3; priT = priAll + 29360128ull; T = 256; t = tpair - 896; }
  priT += (size_t)t * 32768;

  // ---- stage W[t, half*16 .. +16, :, :] -> wb[nd_local][j] bf16 ----
  {
    const floatx4* Wf4 = (const floatx4*)(W + (size_t)t * 32768);
    unsigned int* wb32 = (unsigned int*)wb;  // pitch 36 dwords
#pragma unroll
    for (int it = 0; it < 8; ++it) {
      int idx = it * 256 + tid;              // 0..2047
      int nl = idx >> 7, jp = (idx >> 2) & 31, dq = idx & 3;
      int ng = half * 16 + nl;
      floatx4 fa = Wf4[ng * 256 + (2 * jp) * 4 + dq];
      floatx4 fb = Wf4[ng * 256 + (2 * jp + 1) * 4 + dq];
      int rbase = nl * 16 + dq * 4;
#pragma unroll
      for (int k = 0; k < 4; ++k) {
        unsigned int dw = (unsigned int)f2bf(fa[k]) | ((unsigned int)f2bf(fb[k]) << 16);
        wb32[(rbase + k) * 36 + jp] = dw;
      }
    }
  }

  // ---- A fragments: x[b = mt*16+m][k = s*32 + q*8 + i] -> bf16 ----
  int lane = tid & 63, mt = tid >> 6;
  int m = lane & 15, q = lane >> 4;
  short8 afrag[2];
  {
    const float* xrow = x + ((size_t)(mt * 16 + m) * T + t) * 64;
#pragma unroll
    for (int s = 0; s < 2; ++s) {
      const floatx4* xp = (const floatx4*)(xrow + s * 32 + q * 8);
      floatx4 u0 = xp[0], u1 = xp[1];
      afrag[s][0] = (short)f2bf(u0[0]); afrag[s][1] = (short)f2bf(u0[1]);
      afrag[s][2] = (short)f2bf(u0[2]); afrag[s][3] = (short)f2bf(u0[3]);
      afrag[s][4] = (short)f2bf(u1[0]); afrag[s][5] = (short)f2bf(u1[1]);
      afrag[s][6] = (short)f2bf(u1[2]); afrag[s][7] = (short)f2bf(u1[3]);
    }
  }
  __syncthreads();

  // ---- 16 N-tiles; D layout: row b = mt*16+q*4+reg, col nd = nt*16+m ----
  for (int g = 0; g < 2; ++g) {
#pragma unroll
    for (int k = 0; k < 8; ++k) {
      int nt = g * 8 + k;
      const short8* b0p = (const short8*)&wb[(nt * 16 + m) * 72 + q * 8];
      const short8* b1p = (const short8*)&wb[(nt * 16 + m) * 72 + 32 + q * 8];
      short8 bf0 = *b0p, bf1 = *b1p;
      floatx4 acc = {0.f, 0.f, 0.f, 0.f};
      acc = __builtin_amdgcn_mfma_f32_16x16x32_bf16(afrag[0], bf0, acc, 0, 0, 0);
      acc = __builtin_amdgcn_mfma_f32_16x16x32_bf16(afrag[1], bf1, acc, 0, 0, 0);
#pragma unroll
      for (int reg = 0; reg < 4; ++reg)
        sc[mt][q * 4 + reg][k * 16 + m] = f2bf(acc[reg]);
    }
#pragma unroll
    for (int i = 0; i < 4; ++i) {
      int bl = (lane >> 4) + i * 4;
      int sh = (lane & 15) * 8;
      short8 v = *(const short8*)&sc[mt][bl][sh];
      *(short8*)(priT + (size_t)(mt * 16 + bl) * 512 + half * 256 + g * 128 + sh) = v;
    }
  }
}

// ---------------------------------------------------------------------------
// Block-local routing v3: block = (mod, b); 1024 thr = 16 waves; wave wv owns
// rows [wv*nrw, (wv+1)*nrw). Rows stream through stage[wv][8 slots][1KB] via
// global_load_lds (wave-private: no block barriers in the t-loop). Group
// gl in {0,1} of each wave processes rows 2k+gl; lane = n; softmax over 32
// lanes; LDS-atomic S reduce per pass; Vcum in LDS.
// ---------------------------------------------------------------------------
__global__ __launch_bounds__(1024) void route_kernel(
    const unsigned short* __restrict__ priAll, float* __restrict__ out) {
  __shared__ unsigned short stage[16][8][512];  // 128 KB ring (wave-private)
  __shared__ float Sl[544];                     // [n][d] pitch 17
  __shared__ float Vl[512];

  int blk = blockIdx.x, tid = threadIdx.x;
  int b, T, obase;
  size_t poff;
  if (blk < 64)       { b = blk;       T = 512; poff = 4194304ull;  obase = 32768; }  // audio
  else if (blk < 128) { b = blk - 64;  T = 128; poff = 0;           obase = 0; }      // text
  else if (blk < 192) { b = blk - 128; T = 256; poff = 20971520ull; obase = 65536; }  // video
  else                { b = blk - 192; T = 256; poff = 29360128ull; obase = 98304; }  // frames

  int lane = tid & 63;
  int wv = tid >> 6;       // wave 0..15
  int gl = (tid >> 5) & 1; // group within wave
  int n = tid & 31;
  int nrw = T >> 4;        // rows per wave: 8/32/16/16
  // wave's first row base (shorts); lane offset lane*8 shorts = lane*16 B
  const unsigned short* pw =
      priAll + poff + (size_t)(wv * nrw) * 32768 + (size_t)b * 512;

  if (tid < 512) Vl[tid] = 0.f;

  for (int pass = 0; pass < 4; ++pass) {
    __syncthreads();  // prev pass tail (Sl reads, Vl writes) settled
    if (tid < 544) Sl[tid] = 0.f;
    float Vc[16];
    {
      const floatx4* vp = (const floatx4*)&Vl[n * 16];
      floatx4 v0 = vp[0], v1 = vp[1], v2 = vp[2], v3 = vp[3];
#pragma unroll
      for (int k = 0; k < 4; ++k) {
        Vc[k] = v0[k]; Vc[4 + k] = v1[k]; Vc[8 + k] = v2[k]; Vc[12 + k] = v3[k];
      }
    }
    __syncthreads();  // Sl zeroed before any atomics

    float acc[16];
#pragma unroll
    for (int d = 0; d < 16; ++d) acc[d] = 0.f;

    // prologue: stage rows 0..5 into slots 0..5 (all mods have nrw >= 8)
#pragma unroll
    for (int i = 0; i < 6; ++i)
      stage16(pw + (size_t)i * 32768 + lane * 8, &stage[wv][i][0]);

    int npairs = nrw >> 1;
    for (int k = 0; k < npairs; ++k) {
      // consume rows 2k+gl (group-private) -- vmcnt wait lands here
      const uint4* sp = (const uint4*)&stage[wv][(2 * k + gl) & 7][n * 16];
      uint4 ca = sp[0], cb = sp[1];

      // refill: rows 2k+6, 2k+7 into slots (2k+6)&7, (2k+7)&7
      int r = 2 * k + 6;
      if (r < nrw) stage16(pw + (size_t)r * 32768 + lane * 8, &stage[wv][r & 7][0]);
      if (r + 1 < nrw)
        stage16(pw + (size_t)(r + 1) * 32768 + lane * 8, &stage[wv][(r + 1) & 7][0]);

      float p[16];
      {
        unsigned int wds[8] = {ca.x, ca.y, ca.z, ca.w, cb.x, cb.y, cb.z, cb.w};
#pragma unroll
        for (int kk = 0; kk < 8; ++kk) {
          union { unsigned int u; float f; } lo, hi;
          lo.u = wds[kk] << 16;
          hi.u = wds[kk] & 0xffff0000u;
          p[2 * kk] = lo.f;
          p[2 * kk + 1] = hi.f;
        }
      }
      float logit = 0.f;
#pragma unroll
      for (int d = 0; d < 16; ++d) logit += p[d] * Vc[d];
      float e = __expf(logit);  // |logit| <= ~2: safe without max-sub
      float s = e;
#pragma unroll
      for (int o = 16; o >= 1; o >>= 1) s += __shfl_xor(s, o, 32);
      float rc = e * __builtin_amdgcn_rcpf(s);
#pragma unroll
      for (int d = 0; d < 16; ++d) acc[d] += rc * p[d];
    }

#pragma unroll
    for (int d = 0; d < 16; ++d) atomicAdd(&Sl[n * 17 + d], acc[d]);
    __syncthreads();

    if (tid < 512) {
      float v = tanhf(Sl[(tid >> 4) * 17 + (tid & 15)]);
      if (pass == 3) out[obase + b * 512 + tid] = v;
      else Vl[tid] += v;
    }
  }
}

extern "C" void kernel_launch(void* const* d_in, const int* in_sizes, int n_in,
                              void* d_out, int out_size, void* d_ws, size_t ws_size,
                              hipStream_t stream) {
  const float* x0 = (const float*)d_in[0];
  const float* x1 = (const float*)d_in[1];
  const float* x2 = (const float*)d_in[2];
  const float* x3 = (const float*)d_in[3];
  const float* w0 = (const float*)d_in[4];
  const float* w1 = (const float*)d_in[5];
  const float* w2 = (const float*)d_in[6];
  const float* w3 = (const float*)d_in[7];

  unsigned short* pri = (unsigned short*)d_ws;

  pri_kernel<<<2304, 256, 0, stream>>>(x0, x1, x2, x3, w0, w1, w2, w3, pri);
  route_kernel<<<256, 1024, 0, stream>>>(pri, (float*)d_out);
}